// Round 1
// baseline (232.655 us; speedup 1.0000x reference)
//
#include <hip/hip_runtime.h>
#include <hip/hip_cooperative_groups.h>
#include <math.h>
#include <float.h>

namespace cg = cooperative_groups;

// Problem constants
#define B_ 64
#define M_ 16
#define A_ 128
#define H_ 128
#define P_ 16
#define NAT 100
#define NFP 2048
#define ZDIM (H_ + P_)   // 144

// Fused cooperative kernel geometry
#define FUSED_BLOCKS 512
#define FUSED_THREADS 256
// Phase-1 row groups of 8 rows, never straddling the atom/fp table boundary:
// 13 atom groups (13*8=104, guarded at 100) + 256 fp groups (256*8=2048)
#define NROWGROUPS 269

// Scratch in static device globals — no reliance on ws_size.
__device__ float g_Ta[NAT * H_];       //  51 KB
__device__ float g_Tf[NFP * H_];       //   1 MB
__device__ float g_mol[B_ * M_ * H_];  // 512 KB

// ---------------------------------------------------------------------------
// Fused single-launch kernel: phase1 (table precompute) -> grid.sync ->
// phase2 (per-(b,m) gather/relu/mean) -> grid.sync -> phase3 (head).
// Rationale: the 3-kernel version pays 2 full dispatch boundaries (drain +
// L2 flush + launch latency) for ~15-25 us of actual GPU work.
// ---------------------------------------------------------------------------
__global__ __launch_bounds__(FUSED_THREADS)
void fused_all(const int* __restrict__ af, const int* __restrict__ fpi,
               const float* __restrict__ phys, const float* __restrict__ ratios,
               const float* __restrict__ aemb, const float* __restrict__ femb,
               const float* __restrict__ W_in, const float* __restrict__ b_in,
               const float* __restrict__ ln_g, const float* __restrict__ ln_b,
               const float* __restrict__ W1, const float* __restrict__ b1,
               const float* __restrict__ W2, const float* __restrict__ b2,
               float* __restrict__ out) {
    cg::grid_group grid = cg::this_grid();
    const int t = threadIdx.x;

    __shared__ float e8[8][H_];     // phase 1: 8 embedding rows
    __shared__ int   ia[A_];        // phase 2
    __shared__ int   ifp[A_];
    __shared__ float sh8[8][H_];    // phase 2 partial sums
    __shared__ float wr[M_];        // phase 3
    __shared__ float z[ZDIM];
    __shared__ float zn[ZDIM];
    __shared__ float red[H_];

    // ---------------- Phase 1: T_a = atom_emb@W_in[:128], T_f = fp_emb@W_in[128:]
    // One group of 8 rows per block (blocks >= NROWGROUPS idle). 256 threads:
    // j = col, half = t>>7 owns 4 rows -> 4 FMAs amortize each W load (as k1).
    {
        const int g = blockIdx.x;
        if (g < NROWGROUPS) {
            const int j = t & (H_ - 1);
            const int half = t >> 7;
            const float* emb; const float* W; float* outT; int nrows; int base;
            if (g < 13) { base = g * 8;        emb = aemb; W = W_in;            outT = g_Ta; nrows = NAT; }
            else        { base = (g - 13) * 8; emb = femb; W = W_in + H_ * H_;  outT = g_Tf; nrows = NFP; }
            const int r0 = base + half * 4;
#pragma unroll
            for (int i = 0; i < 4; ++i) {
                const int r = r0 + i;
                e8[half * 4 + i][j] = (r < nrows) ? emb[r * H_ + j] : 0.f;
            }
            __syncthreads();
            float a0 = 0.f, a1 = 0.f, a2 = 0.f, a3 = 0.f;
#pragma unroll 8
            for (int k = 0; k < H_; ++k) {
                const float wk = W[k * H_ + j];        // coalesced, L2-resident
                a0 += e8[half * 4 + 0][k] * wk;        // LDS broadcast reads
                a1 += e8[half * 4 + 1][k] * wk;
                a2 += e8[half * 4 + 2][k] * wk;
                a3 += e8[half * 4 + 3][k] * wk;
            }
            if (r0 + 0 < nrows) outT[(r0 + 0) * H_ + j] = a0;
            if (r0 + 1 < nrows) outT[(r0 + 1) * H_ + j] = a1;
            if (r0 + 2 < nrows) outT[(r0 + 2) * H_ + j] = a2;
            if (r0 + 3 < nrows) outT[(r0 + 3) * H_ + j] = a3;
        }
    }
    grid.sync();

    // ---------------- Phase 2: mol[bm,:] = mean_a relu(T_a[af]+T_f[fp]+b_in)
    // 512 blocks x 2 bm each. thread (q=t&31, s=t>>5): cols 4q..4q+3, atoms
    // a = s, s+8, ... Each half-wave's float4 gather pulls a full 512B row.
    {
        const int q = t & 31, s = t >> 5;      // s in 0..7
        const float4 bj = *(const float4*)&b_in[4 * q];
#pragma unroll
        for (int it = 0; it < 2; ++it) {
            const int bm = blockIdx.x * 2 + it;
            if (t < A_) { ia[t] = af[bm * A_ + t]; ifp[t] = fpi[bm * A_ + t]; }
            __syncthreads();
            float4 acc = make_float4(0.f, 0.f, 0.f, 0.f);
#pragma unroll 8
            for (int a = s; a < A_; a += 8) {
                const int ra = ia[a], rf = ifp[a];
                const float4 va = *(const float4*)&g_Ta[ra * H_ + 4 * q];
                const float4 vf = *(const float4*)&g_Tf[rf * H_ + 4 * q];
                acc.x += fmaxf(va.x + vf.x + bj.x, 0.f);
                acc.y += fmaxf(va.y + vf.y + bj.y, 0.f);
                acc.z += fmaxf(va.z + vf.z + bj.z, 0.f);
                acc.w += fmaxf(va.w + vf.w + bj.w, 0.f);
            }
            *(float4*)&sh8[s][4 * q] = acc;
            __syncthreads();
            if (t < H_) {
                const float m = sh8[0][t] + sh8[1][t] + sh8[2][t] + sh8[3][t]
                              + sh8[4][t] + sh8[5][t] + sh8[6][t] + sh8[7][t];
                g_mol[bm * H_ + t] = m * (1.0f / (float)A_);
            }
            __syncthreads();   // protect ia/ifp/sh8 before next bm
        }
    }
    grid.sync();

    // ---------------- Phase 3: per-batch mix + LayerNorm + MLP head (blocks 0..63)
    if (blockIdx.x < B_) {
        const int b = blockIdx.x;
        const int j = t;
        if (t < M_) wr[t] = ratios[b * M_ + t];
        __syncthreads();
        if (t < H_) {
            float rsum = 0.f;
#pragma unroll
            for (int m = 0; m < M_; ++m) rsum += wr[m];
            const float dinv = 1.0f / (rsum + 1e-8f);
            float acc = 0.f;
#pragma unroll
            for (int m = 0; m < M_; ++m)
                acc += (wr[m] * dinv) * g_mol[(b * M_ + m) * H_ + j];
            z[j] = acc;
            if (j < P_) {
                float accp = 0.f;
#pragma unroll
                for (int m = 0; m < M_; ++m) {
                    float pv = phys[(b * M_ + m) * P_ + j];
                    if (isnan(pv)) pv = 0.f;
                    else if (isinf(pv)) pv = (pv > 0.f) ? 1000.f : -1000.f;
                    accp += (wr[m] * dinv) * pv;
                }
                z[H_ + j] = accp;
            }
        }
        __syncthreads();
        if (t < H_) {
            float sm = 0.f;
#pragma unroll 8
            for (int k = 0; k < ZDIM; ++k) sm += z[k];
            const float mu = sm * (1.0f / (float)ZDIM);
            float s2 = 0.f;
#pragma unroll 8
            for (int k = 0; k < ZDIM; ++k) { const float d = z[k] - mu; s2 += d * d; }
            const float rstd = rsqrtf(s2 * (1.0f / (float)ZDIM) + 1e-5f);
            for (int k = j; k < ZDIM; k += H_)
                zn[k] = (z[k] - mu) * rstd * ln_g[k] + ln_b[k];
        }
        __syncthreads();
        if (t < H_) {
            float a1v = 0.f;
#pragma unroll 8
            for (int k = 0; k < ZDIM; ++k) a1v += zn[k] * W1[k * H_ + j];
            const float h1 = fmaxf(a1v + b1[j], 0.f);
            red[j] = h1 * W2[j];
        }
        __syncthreads();
        if (t == 0) {
            float y = b2[0];
#pragma unroll 8
            for (int k = 0; k < H_; ++k) y += red[k];
            if (isnan(y)) y = 0.f;
            else if (isinf(y)) y = (y > 0.f) ? FLT_MAX : -FLT_MAX;
            out[b] = y;
        }
    }
}

// ---------------------------------------------------------------------------
// Legacy 3-kernel fallback (identical to the previous verified version),
// used only if the cooperative launch is unavailable/rejected.
// ---------------------------------------------------------------------------
#define K1_BLOCKS (NAT / 4 + NFP / 4)   // 25 + 512 = 537
__global__ __launch_bounds__(128)
void k1_precompute(const float* __restrict__ atom_emb,
                   const float* __restrict__ fp_emb,
                   const float* __restrict__ W_in) {
    __shared__ float e[4][H_];
    const int j = threadIdx.x;
    const float* emb; const float* W; float* out; int base;
    if (blockIdx.x < NAT / 4) {
        base = blockIdx.x * 4;             emb = atom_emb; W = W_in;            out = g_Ta;
    } else {
        base = (blockIdx.x - NAT / 4) * 4; emb = fp_emb;   W = W_in + H_ * H_;  out = g_Tf;
    }
#pragma unroll
    for (int r = 0; r < 4; ++r) e[r][j] = emb[(base + r) * H_ + j];
    __syncthreads();
    float a0 = 0.f, a1 = 0.f, a2 = 0.f, a3 = 0.f;
#pragma unroll 8
    for (int k = 0; k < H_; ++k) {
        const float wk = W[k * H_ + j];
        a0 += e[0][k] * wk;
        a1 += e[1][k] * wk;
        a2 += e[2][k] * wk;
        a3 += e[3][k] * wk;
    }
    out[(base + 0) * H_ + j] = a0;
    out[(base + 1) * H_ + j] = a1;
    out[(base + 2) * H_ + j] = a2;
    out[(base + 3) * H_ + j] = a3;
}

__global__ __launch_bounds__(128)
void k2_mol(const int* __restrict__ af, const int* __restrict__ fpi,
            const float* __restrict__ b_in) {
    __shared__ int ia[A_];
    __shared__ int ifp[A_];
    __shared__ float sh[4][H_];
    const int bm = blockIdx.x, t = threadIdx.x;
    const int q = t & 31, s = t >> 5;
    ia[t]  = af[bm * A_ + t];
    ifp[t] = fpi[bm * A_ + t];
    __syncthreads();
    const float4 bj = *(const float4*)&b_in[4 * q];
    float4 acc = make_float4(0.f, 0.f, 0.f, 0.f);
#pragma unroll 8
    for (int a = s; a < A_; a += 4) {
        const int ra = ia[a], rf = ifp[a];
        const float4 va = *(const float4*)&g_Ta[ra * H_ + 4 * q];
        const float4 vf = *(const float4*)&g_Tf[rf * H_ + 4 * q];
        acc.x += fmaxf(va.x + vf.x + bj.x, 0.f);
        acc.y += fmaxf(va.y + vf.y + bj.y, 0.f);
        acc.z += fmaxf(va.z + vf.z + bj.z, 0.f);
        acc.w += fmaxf(va.w + vf.w + bj.w, 0.f);
    }
    *(float4*)&sh[s][4 * q] = acc;
    __syncthreads();
    const int j = t;
    g_mol[bm * H_ + j] =
        (sh[0][j] + sh[1][j] + sh[2][j] + sh[3][j]) * (1.0f / (float)A_);
}

__global__ __launch_bounds__(128)
void k3_head(const float* __restrict__ phys,
             const float* __restrict__ ratios,
             const float* __restrict__ ln_g,
             const float* __restrict__ ln_b,
             const float* __restrict__ W1,
             const float* __restrict__ b1,
             const float* __restrict__ W2,
             const float* __restrict__ b2,
             float* __restrict__ out) {
    const int b = blockIdx.x, j = threadIdx.x;
    __shared__ float w[M_];
    __shared__ float z[ZDIM];
    __shared__ float zn[ZDIM];
    __shared__ float red[H_];

    if (j < M_) w[j] = ratios[b * M_ + j];
    __syncthreads();

    float rsum = 0.f;
#pragma unroll
    for (int m = 0; m < M_; ++m) rsum += w[m];
    const float dinv = 1.0f / (rsum + 1e-8f);

    float acc = 0.f;
#pragma unroll
    for (int m = 0; m < M_; ++m) acc += (w[m] * dinv) * g_mol[(b * M_ + m) * H_ + j];
    z[j] = acc;

    if (j < P_) {
        float accp = 0.f;
#pragma unroll
        for (int m = 0; m < M_; ++m) {
            float pv = phys[(b * M_ + m) * P_ + j];
            if (isnan(pv)) pv = 0.f;
            else if (isinf(pv)) pv = (pv > 0.f) ? 1000.f : -1000.f;
            accp += (w[m] * dinv) * pv;
        }
        z[H_ + j] = accp;
    }
    __syncthreads();

    float s = 0.f;
#pragma unroll 8
    for (int k = 0; k < ZDIM; ++k) s += z[k];
    const float mu = s * (1.0f / (float)ZDIM);
    float s2 = 0.f;
#pragma unroll 8
    for (int k = 0; k < ZDIM; ++k) { float d = z[k] - mu; s2 += d * d; }
    const float rstd = rsqrtf(s2 * (1.0f / (float)ZDIM) + 1e-5f);

    for (int k = j; k < ZDIM; k += H_)
        zn[k] = (z[k] - mu) * rstd * ln_g[k] + ln_b[k];
    __syncthreads();

    float a1 = 0.f;
#pragma unroll 8
    for (int k = 0; k < ZDIM; ++k) a1 += zn[k] * W1[k * H_ + j];
    const float h1 = fmaxf(a1 + b1[j], 0.f);
    red[j] = h1 * W2[j];
    __syncthreads();

    if (j == 0) {
        float y = b2[0];
#pragma unroll 8
        for (int k = 0; k < H_; ++k) y += red[k];
        if (isnan(y)) y = 0.f;
        else if (isinf(y)) y = (y > 0.f) ? FLT_MAX : -FLT_MAX;
        out[b] = y;
    }
}

extern "C" void kernel_launch(void* const* d_in, const int* in_sizes, int n_in,
                              void* d_out, int out_size, void* d_ws, size_t ws_size,
                              hipStream_t stream) {
    (void)in_sizes; (void)n_in; (void)out_size; (void)d_ws; (void)ws_size;
    const int*   af    = (const int*)d_in[0];
    const int*   fpi   = (const int*)d_in[1];
    const float* phys  = (const float*)d_in[2];
    const float* ratio = (const float*)d_in[3];
    const float* aemb  = (const float*)d_in[4];
    const float* femb  = (const float*)d_in[5];
    const float* W_in  = (const float*)d_in[6];
    const float* b_in  = (const float*)d_in[7];
    const float* ln_g  = (const float*)d_in[8];
    const float* ln_b  = (const float*)d_in[9];
    const float* W1    = (const float*)d_in[10];
    const float* b1    = (const float*)d_in[11];
    const float* W2    = (const float*)d_in[12];
    const float* b2    = (const float*)d_in[13];
    float* out = (float*)d_out;

    static int coop = -1;
    if (coop < 0) {
        int dev = 0, v = 0;
        hipGetDevice(&dev);
        if (hipDeviceGetAttribute(&v, hipDeviceAttributeCooperativeLaunch, dev) != hipSuccess)
            v = 0;
        coop = v;
    }

    if (coop) {
        void* args[] = { &af, &fpi, &phys, &ratio, &aemb, &femb, &W_in, &b_in,
                         &ln_g, &ln_b, &W1, &b1, &W2, &b2, &out };
        hipError_t rc = hipLaunchCooperativeKernel(
            fused_all, dim3(FUSED_BLOCKS), dim3(FUSED_THREADS), args, 0u, stream);
        if (rc == hipSuccess) return;
        coop = 0;   // cooperative path rejected -> legacy fallback from now on
    }

    k1_precompute<<<dim3(K1_BLOCKS), dim3(H_), 0, stream>>>(aemb, femb, W_in);
    k2_mol<<<dim3(B_ * M_), dim3(H_), 0, stream>>>(af, fpi, b_in);
    k3_head<<<dim3(B_), dim3(H_), 0, stream>>>(phys, ratio, ln_g, ln_b, W1, b1, W2, b2, out);
}

// Round 2
// 113.373 us; speedup vs baseline: 2.0521x; 2.0521x over previous
//
#include <hip/hip_runtime.h>
#include <math.h>
#include <float.h>

// Problem constants
#define B_ 64
#define M_ 16
#define A_ 128
#define H_ 128
#define P_ 16
#define NAT 100
#define NFP 2048
#define ZDIM (H_ + P_)   // 144

// Scratch in static device globals — no reliance on ws_size.
__device__ float g_Ta[NAT * H_];       //  51 KB
__device__ float g_Tf[NFP * H_];       //   1 MB
__device__ float g_mol[B_ * M_ * H_];  // 512 KB

// K1: T_a = atom_emb @ W_in[:128,:],  T_f = fp_emb @ W_in[128:,:]
// 8 rows per block (amortizes W_in L2 reads 8x: 34 MB -> 17 MB vs 4-row),
// 128 threads, thread j = output col, 8 independent accumulators for ILP.
// Per-element k-order is sequential 0..127 — numerically identical to the
// verified 4-row version (absmax 0.0).
// 13 atom groups (13*8=104, guarded at 100) + 256 fp groups = 269 blocks.
#define K1_BLOCKS (13 + NFP / 8)   // 269
__global__ __launch_bounds__(128)
void k1_precompute(const float* __restrict__ atom_emb,
                   const float* __restrict__ fp_emb,
                   const float* __restrict__ W_in) {
    __shared__ float e[8][H_];
    const int j = threadIdx.x;
    const float* emb; const float* W; float* out; int base; int nrows;
    if (blockIdx.x < 13) {
        base = blockIdx.x * 8;        emb = atom_emb; W = W_in;           out = g_Ta; nrows = NAT;
    } else {
        base = (blockIdx.x - 13) * 8; emb = fp_emb;   W = W_in + H_ * H_; out = g_Tf; nrows = NFP;
    }
#pragma unroll
    for (int r = 0; r < 8; ++r) {
        const int row = base + r;
        e[r][j] = (row < nrows) ? emb[row * H_ + j] : 0.f;
    }
    __syncthreads();
    float a0 = 0.f, a1 = 0.f, a2 = 0.f, a3 = 0.f;
    float a4 = 0.f, a5 = 0.f, a6 = 0.f, a7 = 0.f;
#pragma unroll 8
    for (int k = 0; k < H_; ++k) {
        const float wk = W[k * H_ + j];   // coalesced, L2-resident, read once per block
        a0 += e[0][k] * wk;               // LDS broadcast reads (conflict-free)
        a1 += e[1][k] * wk;
        a2 += e[2][k] * wk;
        a3 += e[3][k] * wk;
        a4 += e[4][k] * wk;
        a5 += e[5][k] * wk;
        a6 += e[6][k] * wk;
        a7 += e[7][k] * wk;
    }
    float acc[8] = {a0, a1, a2, a3, a4, a5, a6, a7};
#pragma unroll
    for (int r = 0; r < 8; ++r)
        if (base + r < nrows) out[(base + r) * H_ + j] = acc[r];
}

// K2: mol[bm,j] = mean_a relu(T_a[af[bm,a],j] + T_f[fp[bm,a],j] + b_in[j])
// One block per (b,m), 128 threads. float4 gathers: thread (s=t>>5, q=t&31)
// owns cols 4q..4q+3 and row-slot s (atoms a = s, s+4, ...). Each half-wave
// instruction fetches one full 512 B table row. unroll 16 keeps ~32 float4
// loads in flight to cover L2 latency (only 2 waves/SIMD resident).
// Summation order identical to the verified version.
__global__ __launch_bounds__(128)
void k2_mol(const int* __restrict__ af, const int* __restrict__ fpi,
            const float* __restrict__ b_in) {
    __shared__ int ia[A_];
    __shared__ int ifp[A_];
    __shared__ float sh[4][H_];
    const int bm = blockIdx.x, t = threadIdx.x;
    const int q = t & 31, s = t >> 5;
    ia[t]  = af[bm * A_ + t];
    ifp[t] = fpi[bm * A_ + t];
    __syncthreads();
    const float4 bj = *(const float4*)&b_in[4 * q];
    float4 acc = make_float4(0.f, 0.f, 0.f, 0.f);
#pragma unroll 16
    for (int a = s; a < A_; a += 4) {
        const int ra = ia[a], rf = ifp[a];
        const float4 va = *(const float4*)&g_Ta[ra * H_ + 4 * q];
        const float4 vf = *(const float4*)&g_Tf[rf * H_ + 4 * q];
        acc.x += fmaxf(va.x + vf.x + bj.x, 0.f);
        acc.y += fmaxf(va.y + vf.y + bj.y, 0.f);
        acc.z += fmaxf(va.z + vf.z + bj.z, 0.f);
        acc.w += fmaxf(va.w + vf.w + bj.w, 0.f);
    }
    *(float4*)&sh[s][4 * q] = acc;
    __syncthreads();
    const int j = t;
    g_mol[bm * H_ + j] =
        (sh[0][j] + sh[1][j] + sh[2][j] + sh[3][j]) * (1.0f / (float)A_);
}

// K3: per-batch mix + LayerNorm + MLP head. One block per b, 128 threads.
__global__ __launch_bounds__(128)
void k3_head(const float* __restrict__ phys,
             const float* __restrict__ ratios,
             const float* __restrict__ ln_g,
             const float* __restrict__ ln_b,
             const float* __restrict__ W1,
             const float* __restrict__ b1,
             const float* __restrict__ W2,
             const float* __restrict__ b2,
             float* __restrict__ out) {
    const int b = blockIdx.x, j = threadIdx.x;
    __shared__ float w[M_];
    __shared__ float z[ZDIM];
    __shared__ float zn[ZDIM];
    __shared__ float red[H_];

    if (j < M_) w[j] = ratios[b * M_ + j];
    __syncthreads();

    float rsum = 0.f;
#pragma unroll
    for (int m = 0; m < M_; ++m) rsum += w[m];
    const float dinv = 1.0f / (rsum + 1e-8f);

    // mix_h
    float acc = 0.f;
#pragma unroll
    for (int m = 0; m < M_; ++m) acc += (w[m] * dinv) * g_mol[(b * M_ + m) * H_ + j];
    z[j] = acc;

    // mix_p (threads 0..15)
    if (j < P_) {
        float accp = 0.f;
#pragma unroll
        for (int m = 0; m < M_; ++m) {
            float pv = phys[(b * M_ + m) * P_ + j];
            if (isnan(pv)) pv = 0.f;
            else if (isinf(pv)) pv = (pv > 0.f) ? 1000.f : -1000.f;
            accp += (w[m] * dinv) * pv;
        }
        z[H_ + j] = accp;
    }
    __syncthreads();

    // LayerNorm stats (redundant per-thread; broadcast LDS reads, cheap)
    float s = 0.f;
#pragma unroll 8
    for (int k = 0; k < ZDIM; ++k) s += z[k];
    const float mu = s * (1.0f / (float)ZDIM);
    float s2 = 0.f;
#pragma unroll 8
    for (int k = 0; k < ZDIM; ++k) { float d = z[k] - mu; s2 += d * d; }
    const float rstd = rsqrtf(s2 * (1.0f / (float)ZDIM) + 1e-5f);

    for (int k = j; k < ZDIM; k += H_)
        zn[k] = (z[k] - mu) * rstd * ln_g[k] + ln_b[k];
    __syncthreads();

    // h1 = relu(zn @ W1 + b1); thread j = column j
    float a1 = 0.f;
#pragma unroll 8
    for (int k = 0; k < ZDIM; ++k) a1 += zn[k] * W1[k * H_ + j];
    const float h1 = fmaxf(a1 + b1[j], 0.f);
    red[j] = h1 * W2[j];
    __syncthreads();

    if (j == 0) {
        float y = b2[0];
#pragma unroll 8
        for (int k = 0; k < H_; ++k) y += red[k];
        // jnp.nan_to_num: nan->0, +inf->FLT_MAX, -inf->-FLT_MAX
        if (isnan(y)) y = 0.f;
        else if (isinf(y)) y = (y > 0.f) ? FLT_MAX : -FLT_MAX;
        out[b] = y;
    }
}

extern "C" void kernel_launch(void* const* d_in, const int* in_sizes, int n_in,
                              void* d_out, int out_size, void* d_ws, size_t ws_size,
                              hipStream_t stream) {
    (void)in_sizes; (void)n_in; (void)out_size; (void)d_ws; (void)ws_size;
    const int*   af    = (const int*)d_in[0];
    const int*   fpi   = (const int*)d_in[1];
    const float* phys  = (const float*)d_in[2];
    const float* ratio = (const float*)d_in[3];
    const float* aemb  = (const float*)d_in[4];
    const float* femb  = (const float*)d_in[5];
    const float* W_in  = (const float*)d_in[6];
    const float* b_in  = (const float*)d_in[7];
    const float* ln_g  = (const float*)d_in[8];
    const float* ln_b  = (const float*)d_in[9];
    const float* W1    = (const float*)d_in[10];
    const float* b1    = (const float*)d_in[11];
    const float* W2    = (const float*)d_in[12];
    const float* b2    = (const float*)d_in[13];
    float* out = (float*)d_out;

    k1_precompute<<<dim3(K1_BLOCKS), dim3(H_), 0, stream>>>(aemb, femb, W_in);
    k2_mol<<<dim3(B_ * M_), dim3(H_), 0, stream>>>(af, fpi, b_in);
    k3_head<<<dim3(B_), dim3(H_), 0, stream>>>(phys, ratio, ln_g, ln_b, W1, b1, W2, b2, out);
}

// Round 3
// 108.826 us; speedup vs baseline: 2.1379x; 1.0418x over previous
//
#include <hip/hip_runtime.h>
#include <math.h>
#include <float.h>

// Problem constants
#define B_ 64
#define M_ 16
#define A_ 128
#define H_ 128
#define P_ 16
#define NAT 100
#define NFP 2048
#define ZDIM (H_ + P_)   // 144

// Scratch in static device globals — no reliance on ws_size.
__device__ float g_Ta[NAT * H_];       //  51 KB
__device__ float g_Tf[NFP * H_];       //   1 MB
__device__ float g_mol[B_ * M_ * H_];  // 512 KB

// K1: T_a = atom_emb @ W_in[:128,:],  T_f = fp_emb @ W_in[128:,:]
// 4 rows per block (amortizes W_in L2 reads 4x: 137 MB -> 34 MB), 128 threads,
// thread j = output col, 4 independent accumulators for ILP.
// Blocks 0..24 cover T_a's 100 rows exactly; blocks 25..536 cover T_f's 2048.
// NOTE (R2 post-mortem): the 8-row variant + k2 unroll-16 measured 113.4 us
// vs this config's 108.3 — codegen perturbation outweighs the ~1 us of L2
// traffic saved. Keep this twice-verified form.
#define K1_BLOCKS (NAT / 4 + NFP / 4)   // 25 + 512 = 537
__global__ __launch_bounds__(128)
void k1_precompute(const float* __restrict__ atom_emb,
                   const float* __restrict__ fp_emb,
                   const float* __restrict__ W_in) {
    __shared__ float e[4][H_];
    const int j = threadIdx.x;
    const float* emb; const float* W; float* out; int base;
    if (blockIdx.x < NAT / 4) {
        base = blockIdx.x * 4;           emb = atom_emb; W = W_in;            out = g_Ta;
    } else {
        base = (blockIdx.x - NAT / 4) * 4; emb = fp_emb;  W = W_in + H_ * H_; out = g_Tf;
    }
#pragma unroll
    for (int r = 0; r < 4; ++r) e[r][j] = emb[(base + r) * H_ + j];
    __syncthreads();
    float a0 = 0.f, a1 = 0.f, a2 = 0.f, a3 = 0.f;
#pragma unroll 8
    for (int k = 0; k < H_; ++k) {
        const float wk = W[k * H_ + j];   // coalesced, L1/L2-resident
        a0 += e[0][k] * wk;               // LDS broadcast reads (conflict-free)
        a1 += e[1][k] * wk;
        a2 += e[2][k] * wk;
        a3 += e[3][k] * wk;
    }
    out[(base + 0) * H_ + j] = a0;
    out[(base + 1) * H_ + j] = a1;
    out[(base + 2) * H_ + j] = a2;
    out[(base + 3) * H_ + j] = a3;
}

// K2: mol[bm,j] = mean_a relu(T_a[af[bm,a],j] + T_f[fp[bm,a],j] + b_in[j])
// One block per (b,m), 128 threads. float4 gathers: thread (s=t>>5, q=t&31)
// owns cols 4q..4q+3 and row-slot s (atoms a = s, s+4, ...). Each wave
// instruction fetches two full 512 B table rows. Partial sums reduced via LDS.
__global__ __launch_bounds__(128)
void k2_mol(const int* __restrict__ af, const int* __restrict__ fpi,
            const float* __restrict__ b_in) {
    __shared__ int ia[A_];
    __shared__ int ifp[A_];
    __shared__ float sh[4][H_];
    const int bm = blockIdx.x, t = threadIdx.x;
    const int q = t & 31, s = t >> 5;
    ia[t]  = af[bm * A_ + t];
    ifp[t] = fpi[bm * A_ + t];
    __syncthreads();
    const float4 bj = *(const float4*)&b_in[4 * q];
    float4 acc = make_float4(0.f, 0.f, 0.f, 0.f);
#pragma unroll 8
    for (int a = s; a < A_; a += 4) {
        const int ra = ia[a], rf = ifp[a];
        const float4 va = *(const float4*)&g_Ta[ra * H_ + 4 * q];
        const float4 vf = *(const float4*)&g_Tf[rf * H_ + 4 * q];
        acc.x += fmaxf(va.x + vf.x + bj.x, 0.f);
        acc.y += fmaxf(va.y + vf.y + bj.y, 0.f);
        acc.z += fmaxf(va.z + vf.z + bj.z, 0.f);
        acc.w += fmaxf(va.w + vf.w + bj.w, 0.f);
    }
    *(float4*)&sh[s][4 * q] = acc;
    __syncthreads();
    const int j = t;
    g_mol[bm * H_ + j] =
        (sh[0][j] + sh[1][j] + sh[2][j] + sh[3][j]) * (1.0f / (float)A_);
}

// K3: per-batch mix + LayerNorm + MLP head. One block per b, 128 threads.
__global__ __launch_bounds__(128)
void k3_head(const float* __restrict__ phys,
             const float* __restrict__ ratios,
             const float* __restrict__ ln_g,
             const float* __restrict__ ln_b,
             const float* __restrict__ W1,
             const float* __restrict__ b1,
             const float* __restrict__ W2,
             const float* __restrict__ b2,
             float* __restrict__ out) {
    const int b = blockIdx.x, j = threadIdx.x;
    __shared__ float w[M_];
    __shared__ float z[ZDIM];
    __shared__ float zn[ZDIM];
    __shared__ float red[H_];

    if (j < M_) w[j] = ratios[b * M_ + j];
    __syncthreads();

    float rsum = 0.f;
#pragma unroll
    for (int m = 0; m < M_; ++m) rsum += w[m];
    const float dinv = 1.0f / (rsum + 1e-8f);

    // mix_h
    float acc = 0.f;
#pragma unroll
    for (int m = 0; m < M_; ++m) acc += (w[m] * dinv) * g_mol[(b * M_ + m) * H_ + j];
    z[j] = acc;

    // mix_p (threads 0..15)
    if (j < P_) {
        float accp = 0.f;
#pragma unroll
        for (int m = 0; m < M_; ++m) {
            float pv = phys[(b * M_ + m) * P_ + j];
            if (isnan(pv)) pv = 0.f;
            else if (isinf(pv)) pv = (pv > 0.f) ? 1000.f : -1000.f;
            accp += (w[m] * dinv) * pv;
        }
        z[H_ + j] = accp;
    }
    __syncthreads();

    // LayerNorm stats (redundant per-thread; broadcast LDS reads, cheap)
    float s = 0.f;
#pragma unroll 8
    for (int k = 0; k < ZDIM; ++k) s += z[k];
    const float mu = s * (1.0f / (float)ZDIM);
    float s2 = 0.f;
#pragma unroll 8
    for (int k = 0; k < ZDIM; ++k) { float d = z[k] - mu; s2 += d * d; }
    const float rstd = rsqrtf(s2 * (1.0f / (float)ZDIM) + 1e-5f);

    for (int k = j; k < ZDIM; k += H_)
        zn[k] = (z[k] - mu) * rstd * ln_g[k] + ln_b[k];
    __syncthreads();

    // h1 = relu(zn @ W1 + b1); thread j = column j
    float a1 = 0.f;
#pragma unroll 8
    for (int k = 0; k < ZDIM; ++k) a1 += zn[k] * W1[k * H_ + j];
    const float h1 = fmaxf(a1 + b1[j], 0.f);
    red[j] = h1 * W2[j];
    __syncthreads();

    if (j == 0) {
        float y = b2[0];
#pragma unroll 8
        for (int k = 0; k < H_; ++k) y += red[k];
        // jnp.nan_to_num: nan->0, +inf->FLT_MAX, -inf->-FLT_MAX
        if (isnan(y)) y = 0.f;
        else if (isinf(y)) y = (y > 0.f) ? FLT_MAX : -FLT_MAX;
        out[b] = y;
    }
}

extern "C" void kernel_launch(void* const* d_in, const int* in_sizes, int n_in,
                              void* d_out, int out_size, void* d_ws, size_t ws_size,
                              hipStream_t stream) {
    (void)in_sizes; (void)n_in; (void)out_size; (void)d_ws; (void)ws_size;
    const int*   af    = (const int*)d_in[0];
    const int*   fpi   = (const int*)d_in[1];
    const float* phys  = (const float*)d_in[2];
    const float* ratio = (const float*)d_in[3];
    const float* aemb  = (const float*)d_in[4];
    const float* femb  = (const float*)d_in[5];
    const float* W_in  = (const float*)d_in[6];
    const float* b_in  = (const float*)d_in[7];
    const float* ln_g  = (const float*)d_in[8];
    const float* ln_b  = (const float*)d_in[9];
    const float* W1    = (const float*)d_in[10];
    const float* b1    = (const float*)d_in[11];
    const float* W2    = (const float*)d_in[12];
    const float* b2    = (const float*)d_in[13];
    float* out = (float*)d_out;

    k1_precompute<<<dim3(K1_BLOCKS), dim3(H_), 0, stream>>>(aemb, femb, W_in);
    k2_mol<<<dim3(B_ * M_), dim3(H_), 0, stream>>>(af, fpi, b_in);
    k3_head<<<dim3(B_), dim3(H_), 0, stream>>>(phys, ratio, ln_g, ln_b, W1, b1, W2, b2, out);
}